// Round 4
// baseline (761.439 us; speedup 1.0000x reference)
//
#include <hip/hip_runtime.h>
#include <cstdint>
#include <cstddef>

using u16 = unsigned short;
using u32 = unsigned int;

// ---------------- helpers ----------------
__device__ __forceinline__ float bf2f(u16 u){
  union { u32 i; float f; } x; x.i = ((u32)u) << 16; return x.f;
}
__device__ __forceinline__ u16 f2bf(float f){
  union { float f; u32 i; } x; x.f = f;
  u32 r = x.i + 0x7fffu + ((x.i >> 16) & 1u);
  return (u16)(r >> 16);
}
__device__ __forceinline__ float gelu_f(float x){
  return 0.5f * x * (1.0f + erff(x * 0.70710678118654752f));
}
__device__ __forceinline__ void gld16(const void* g, void* l){
  // async global->LDS, 16B/lane; LDS dst = wave-uniform base + lane*16
  __builtin_amdgcn_global_load_lds((__attribute__((address_space(1))) void*)(void*)g,
                                   (__attribute__((address_space(3))) void*)l, 16, 0, 0);
}

typedef __bf16 bf16x8 __attribute__((ext_vector_type(8)));
typedef float  f32x4  __attribute__((ext_vector_type(4)));
typedef u16    u16x4  __attribute__((ext_vector_type(4)));

// ---------------- weight transpose + cast: src fp32 [R,C] -> dst bf16 [C,R] ----------------
__global__ __launch_bounds__(256) void k_transpose(const float* __restrict__ src,
                                                   u16* __restrict__ dst, int R, int C){
  __shared__ u16 tile[32][33];
  int bx = blockIdx.x * 32;
  int by = blockIdx.y * 32;
  int tx = threadIdx.x & 31;
  int ty = threadIdx.x >> 5;
  for (int r = ty; r < 32; r += 8)
    tile[r][tx] = f2bf(src[(size_t)(by + r) * C + bx + tx]);
  __syncthreads();
  for (int r = ty; r < 32; r += 8)
    dst[(size_t)(bx + r) * R + by + tx] = tile[tx][r];
}

// ---------------- layernorm over last dim (cols = 1024 or 512), optional gelu, bf16 out ----------------
template<bool IN_F32, bool DO_GELU>
__global__ __launch_bounds__(256) void k_layernorm(const void* __restrict__ inp,
    const float* __restrict__ w, const float* __restrict__ bsh,
    u16* __restrict__ out, int cols, float eps){
  int row = blockIdx.x, t = threadIdx.x;
  size_t base = (size_t)row * cols;
  const float* inf = (const float*)inp;
  const u16*  inb = (const u16*)inp;
  float v[4];
  int ep = cols >> 8;
  float s = 0.f, ss = 0.f;
  for (int e = 0; e < ep; ++e){
    int idx = t + (e << 8);
    float x = IN_F32 ? inf[base + idx] : bf2f(inb[base + idx]);
    v[e] = x; s += x; ss += x * x;
  }
#pragma unroll
  for (int off = 1; off < 64; off <<= 1){
    s  += __shfl_xor(s, off, 64);
    ss += __shfl_xor(ss, off, 64);
  }
  __shared__ float red[8];
  int wv = t >> 6;
  if ((t & 63) == 0){ red[wv] = s; red[4 + wv] = ss; }
  __syncthreads();
  s  = red[0] + red[1] + red[2] + red[3];
  ss = red[4] + red[5] + red[6] + red[7];
  float inv = 1.f / (float)cols;
  float mean = s * inv;
  float var = ss * inv - mean * mean;
  float rs = rsqrtf(var + eps);
  for (int e = 0; e < ep; ++e){
    int idx = t + (e << 8);
    float y = (v[e] - mean) * rs * w[idx] + bsh[idx];
    if (DO_GELU) y = gelu_f(y);
    out[base + idx] = f2bf(y);
  }
}

// ---------------- final: out(fp32) = x2(bf16) + LN(c3; ln3) , cols=1024 ----------------
__global__ __launch_bounds__(256) void k_final(const u16* __restrict__ c3,
    const u16* __restrict__ x2, const float* __restrict__ w,
    const float* __restrict__ bsh, float* __restrict__ out){
  int row = blockIdx.x, t = threadIdx.x;
  size_t base = (size_t)row << 10;
  float v[4];
  float s = 0.f, ss = 0.f;
#pragma unroll
  for (int e = 0; e < 4; ++e){
    int idx = t + (e << 8);
    float x = bf2f(c3[base + idx]);
    v[e] = x; s += x; ss += x * x;
  }
#pragma unroll
  for (int off = 1; off < 64; off <<= 1){
    s  += __shfl_xor(s, off, 64);
    ss += __shfl_xor(ss, off, 64);
  }
  __shared__ float red[8];
  int wv = t >> 6;
  if ((t & 63) == 0){ red[wv] = s; red[4 + wv] = ss; }
  __syncthreads();
  s  = red[0] + red[1] + red[2] + red[3];
  ss = red[4] + red[5] + red[6] + red[7];
  float mean = s * (1.f/1024.f);
  float var = ss * (1.f/1024.f) - mean * mean;
  float rs = rsqrtf(var + 1e-6f);
#pragma unroll
  for (int e = 0; e < 4; ++e){
    int idx = t + (e << 8);
    float y = (v[e] - mean) * rs * w[idx] + bsh[idx];
    out[base + idx] = bf2f(x2[base + idx]) + y;
  }
}

// ---------------- MFMA GEMM: C[M,N] = A[M,K](bf16) * Bt[N,K]^T(bf16) (+fp32 bias/res, gelu) ----------------
// m97 structure: 128x128 tile, BK=32, 4 waves (2x2 of 64x64), global_load_lds width 16.
// XCD-aware bijective block swizzle (T1/m204): contiguous chunks of the y-major linear
// grid per XCD so tiles sharing an A-panel land in the same XCD L2.
template<bool BIAS, bool GELU, bool RES, bool OUTB, bool OUTF>
__global__ __launch_bounds__(256, 2) void k_gemm(
    const u16* __restrict__ A, const u16* __restrict__ Bt,
    const float* __restrict__ bias, const float* __restrict__ resf,
    u16* __restrict__ outb, float* __restrict__ outf, int N, int K)
{
  __shared__ __align__(16) u16 As[128 * 32];
  __shared__ __align__(16) u16 Bs[128 * 32];
  int t = threadIdx.x, lane = t & 63, wv = t >> 6;

  int nbx = gridDim.x;
  int nwg = nbx * gridDim.y;
  int li  = blockIdx.y * nbx + blockIdx.x;
  int qc = nwg >> 3, rc = nwg & 7;
  int xcd = li & 7, jj = li >> 3;
  int wg = (xcd < rc ? xcd * (qc + 1) : rc * (qc + 1) + (xcd - rc) * qc) + jj;
  int byy = wg / nbx;
  int bxx = wg - byy * nbx;
  int m0 = byy << 7, n0 = bxx << 7;

  int wm = (wv >> 1) << 6, wn = (wv & 1) << 6;

  f32x4 acc[4][4];
  const f32x4 z4 = {0.f, 0.f, 0.f, 0.f};
#pragma unroll
  for (int i = 0; i < 4; ++i)
#pragma unroll
    for (int j = 0; j < 4; ++j) acc[i][j] = z4;

  int srow = (wv << 5) + (lane >> 2);
  int skp  = (lane & 3) << 3;
  const u16* Ag = A  + (size_t)(m0 + srow) * K + skp;
  const u16* Bg = Bt + (size_t)(n0 + srow) * K + skp;
  u16* As0 = &As[(wv << 5) * 32];
  u16* As1 = As0 + 16 * 32;
  u16* Bs0 = &Bs[(wv << 5) * 32];
  u16* Bs1 = Bs0 + 16 * 32;
  const size_t rowskip = (size_t)16 * K;

  int fr = lane & 15, fq = (lane >> 4) << 3;

  for (int k0 = 0; k0 < K; k0 += 32){
    gld16(Ag + k0, As0);
    gld16(Ag + rowskip + k0, As1);
    gld16(Bg + k0, Bs0);
    gld16(Bg + rowskip + k0, Bs1);
    __syncthreads();
    bf16x8 af[4], bfr[4];
#pragma unroll
    for (int i = 0; i < 4; ++i)
      af[i] = *(const bf16x8*)&As[(wm + i * 16 + fr) * 32 + fq];
#pragma unroll
    for (int j = 0; j < 4; ++j)
      bfr[j] = *(const bf16x8*)&Bs[(wn + j * 16 + fr) * 32 + fq];
#pragma unroll
    for (int i = 0; i < 4; ++i)
#pragma unroll
      for (int j = 0; j < 4; ++j)
        acc[i][j] = __builtin_amdgcn_mfma_f32_16x16x32_bf16(af[i], bfr[j], acc[i][j], 0, 0, 0);
    __syncthreads();
  }

  int rr = (lane >> 4) << 2;
  int cc = lane & 15;
#pragma unroll
  for (int i = 0; i < 4; ++i)
#pragma unroll
    for (int j = 0; j < 4; ++j){
      int gc = n0 + wn + j * 16 + cc;
      float bb = BIAS ? bias[gc] : 0.f;
#pragma unroll
      for (int r = 0; r < 4; ++r){
        int gr = m0 + wm + i * 16 + rr + r;
        size_t idx = (size_t)gr * N + gc;
        float vv = acc[i][j][r] + bb;
        if (RES) vv += resf[idx];
        if (GELU) vv = gelu_f(vv);
        if (OUTF) outf[idx] = vv;
        if (OUTB) outb[idx] = f2bf(vv);
      }
    }
}

// ---------------- V pre-transpose: qkvbuf V slice -> vtg[bnh][64 d][832 j] (bf16, j zero-padded) ----------------
__global__ __launch_bounds__(256) void k_vtrans(const u16* __restrict__ qkv, u16* __restrict__ vtg){
  __shared__ u32 tile[64][33];
  int bnh = blockIdx.x;            // 0..127
  int st  = blockIdx.y;            // 0..12
  int b = bnh >> 4, nh = bnh & 15;
  int t = threadIdx.x;
  int tx = t & 31;                 // dword column (2 u16)
  int ty = t >> 5;                 // 0..7
  const u16* src = qkv + (size_t)b * 784 * 3072 + 2048 + nh * 64;
  int s0 = st << 6;
  for (int r = ty; r < 64; r += 8){
    int s = s0 + r;
    u32 val = 0u;
    if (s < 784) val = *(const u32*)(src + (size_t)s * 3072 + tx * 2);
    tile[r][tx] = val;
  }
  __syncthreads();
  u16* dst = vtg + (size_t)bnh * 64 * 832 + s0;
  for (int d = ty; d < 64; d += 8){
    u32 lo = tile[2 * tx][d >> 1];
    u32 hi = tile[2 * tx + 1][d >> 1];
    u16 a  = (d & 1) ? (u16)(lo >> 16) : (u16)lo;
    u16 bb = (d & 1) ? (u16)(hi >> 16) : (u16)hi;
    u32 pk = (u32)a | ((u32)bb << 16);
    *(u32*)(dst + (size_t)d * 832 + 2 * tx) = pk;
  }
}

// ---------------- MFMA flash attention v6: 1-wave blocks, zero barriers, XCD-chunked grid ----------------
// grid = 3200 = 8 XCD chunks x 400; 400/25 = 16 (b,nh) heads per XCD -> K/V L2-resident per XCD.
// Each 64-thread block = 1 wave owning 32 q-rows; all LDS strictly wave-private.
#define PST 72
#define GT  36
#define LOG2E 1.4426950408889634f
__global__ __launch_bounds__(64, 3) void k_attn6(const u16* __restrict__ qkv,
    const float* __restrict__ relh, const float* __restrict__ relw,
    const u16* __restrict__ vtg, u16* __restrict__ out)
{
  __shared__ __align__(16) u16 p_s[32 * PST];    // 4608 B
  __shared__ __align__(16) u16 gh_t[28 * GT];    // 2016 B  (transposed, pre-scaled by log2e)
  __shared__ __align__(16) u16 gw_t[28 * GT];    // 2016 B

  const int lane = threadIdx.x & 63;
  // XCD-chunked decode: 25 q-subtiles per (b,nh) (rows >= 800 dropped entirely)
  int i = blockIdx.x;
  int o = (i & 7) * 400 + (i >> 3);
  int bnh = o / 25;
  int rem = o - bnh * 25;
  const int b = bnh >> 4, nh = bnh & 15;
  const int q0 = rem << 5;               // 0,32,...,768
  const size_t rowbase = (size_t)b * 784;
  const int fr = lane & 15;
  const int fq = lane >> 4;

  // Q fragments (registers)
  bf16x8 qf[2][2];
#pragma unroll
  for (int mf = 0; mf < 2; ++mf)
#pragma unroll
    for (int ks = 0; ks < 2; ++ks){
      int row = q0 + mf * 16 + fr;
      if (row < 784){
        qf[mf][ks] = *(const bf16x8*)(qkv + (rowbase + row) * 3072 + nh * 64 + fq * 8 + ks * 32);
      } else {
        uint4 z = {0u,0u,0u,0u}; qf[mf][ks] = *(bf16x8*)&z;
      }
    }

  const f32x4 z4 = {0.f,0.f,0.f,0.f};

  // ---- decomposed rel-pos bias via MFMA; Rh/Rw B-fragments straight from global (f32 -> bf16) ----
#pragma unroll
  for (int which = 0; which < 2; ++which){
    const float* R = which ? relw : relh;
    f32x4 G[2][4];
#pragma unroll
    for (int mf = 0; mf < 2; ++mf)
#pragma unroll
      for (int nf = 0; nf < 4; ++nf) G[mf][nf] = z4;
#pragma unroll
    for (int nf = 0; nf < 4; ++nf){
      int row = nf * 16 + fr;
      bf16x8 rf0, rf1;
      if (row < 55){
        const float* p = R + row * 64 + fq * 8;
        u16 tmp[16];
#pragma unroll
        for (int e = 0; e < 8; ++e) tmp[e]     = f2bf(p[e]);
#pragma unroll
        for (int e = 0; e < 8; ++e) tmp[8 + e] = f2bf(p[32 + e]);
        rf0 = *(bf16x8*)tmp; rf1 = *(bf16x8*)(tmp + 8);
      } else {
        uint4 z = {0u,0u,0u,0u}; rf0 = *(bf16x8*)&z; rf1 = rf0;
      }
#pragma unroll
      for (int mf = 0; mf < 2; ++mf){
        G[mf][nf] = __builtin_amdgcn_mfma_f32_16x16x32_bf16(qf[mf][0], rf0, G[mf][nf], 0, 0, 0);
        G[mf][nf] = __builtin_amdgcn_mfma_f32_16x16x32_bf16(qf[mf][1], rf1, G[mf][nf], 0, 0, 0);
      }
    }
    u16* gt = which ? gw_t : gh_t;
#pragma unroll
    for (int mf = 0; mf < 2; ++mf)
#pragma unroll
      for (int r = 0; r < 4; ++r){
        int lr = mf * 16 + fq * 4 + r;
        int grow = q0 + lr;
        int hq = grow / 28;
        int coord = which ? (grow - hq * 28) : hq;
#pragma unroll
        for (int nf = 0; nf < 4; ++nf){
          int j = nf * 16 + fr;
          int kk = coord + 27 - j;
          if ((unsigned)kk < 28u) gt[kk * GT + lr] = f2bf(G[mf][nf][r] * LOG2E);
        }
      }
  }
  // no barrier needed: all LDS deps are within this single wave (waitcnt-ordered)

  f32x4 acc[2][5];
#pragma unroll
  for (int mf = 0; mf < 2; ++mf)
#pragma unroll
    for (int nf = 0; nf < 5; ++nf) acc[mf][nf] = z4;

  u16 onesu[8];
#pragma unroll
  for (int e = 0; e < 8; ++e) onesu[e] = 0x3f80;
  bf16x8 onesf = *(bf16x8*)onesu;

  const u16* kgb = qkv + rowbase * 3072 + 1024 + nh * 64 + fq * 8;
  const u16* vgb = vtg + ((size_t)bnh * 64 + fr) * 832 + fq * 8;

  const float SSC = 0.125f * LOG2E;

  for (int kt = 0; kt < 13; ++kt){
    const int ktb = kt << 6;

    // V fragments: issue first, consumed last (latency hides under QK^T + softmax)
    bf16x8 vf[2][4];
#pragma unroll
    for (int ks = 0; ks < 2; ++ks)
#pragma unroll
      for (int nf = 0; nf < 4; ++nf)
        vf[ks][nf] = *(const bf16x8*)(vgb + (size_t)(nf * 16) * 832 + ktb + ks * 32);

    // K fragments
    bf16x8 kf[4][2];
#pragma unroll
    for (int nf = 0; nf < 4; ++nf){
      int jg = ktb + nf * 16 + fr;
      int jc = jg < 784 ? jg : 783;
      const u16* kp = kgb + (size_t)jc * 3072;
      kf[nf][0] = *(const bf16x8*)kp;
      kf[nf][1] = *(const bf16x8*)(kp + 32);
    }

    // per-nf QK^T -> softmax -> P store (short S liveness; 4 independent chains)
#pragma unroll
    for (int nf = 0; nf < 4; ++nf){
      f32x4 S[2];
#pragma unroll
      for (int mf = 0; mf < 2; ++mf){
        f32x4 s = z4;
        s = __builtin_amdgcn_mfma_f32_16x16x32_bf16(qf[mf][0], kf[nf][0], s, 0, 0, 0);
        s = __builtin_amdgcn_mfma_f32_16x16x32_bf16(qf[mf][1], kf[nf][1], s, 0, 0, 0);
        S[mf] = s;
      }
      int jg = ktb + nf * 16 + fr;
      int h = jg / 28;
      int w = jg - h * 28;
      bool val = (jg < 784);
#pragma unroll
      for (int mf = 0; mf < 2; ++mf){
        int lrb = mf * 16 + fq * 4;
        u16x4 h4 = *(const u16x4*)&gh_t[h * GT + lrb];
        u16x4 w4 = *(const u16x4*)&gw_t[w * GT + lrb];
#pragma unroll
        for (int r = 0; r < 4; ++r){
          float p = 0.f;
          if (val)
            p = exp2f(fmaf(SSC, S[mf][r], bf2f(h4[r]) + bf2f(w4[r])));
          p_s[(lrb + r) * PST + nf * 16 + fr] = f2bf(p);
        }
      }
    }

    // PV: P from wave-private LDS rows, V from registers
#pragma unroll
    for (int ks = 0; ks < 2; ++ks){
      bf16x8 pf0 = *(const bf16x8*)&p_s[(fr) * PST + fq * 8 + ks * 32];
      bf16x8 pf1 = *(const bf16x8*)&p_s[(16 + fr) * PST + fq * 8 + ks * 32];
#pragma unroll
      for (int nf = 0; nf < 4; ++nf){
        acc[0][nf] = __builtin_amdgcn_mfma_f32_16x16x32_bf16(pf0, vf[ks][nf], acc[0][nf], 0, 0, 0);
        acc[1][nf] = __builtin_amdgcn_mfma_f32_16x16x32_bf16(pf1, vf[ks][nf], acc[1][nf], 0, 0, 0);
      }
      acc[0][4] = __builtin_amdgcn_mfma_f32_16x16x32_bf16(pf0, onesf, acc[0][4], 0, 0, 0);
      acc[1][4] = __builtin_amdgcn_mfma_f32_16x16x32_bf16(pf1, onesf, acc[1][4], 0, 0, 0);
    }
  }

#pragma unroll
  for (int mf = 0; mf < 2; ++mf)
#pragma unroll
    for (int r = 0; r < 4; ++r){
      int row = q0 + mf * 16 + fq * 4 + r;
      if (row < 784){
        float inv = 1.f / acc[mf][4][r];   // ones-fragment: every column holds the row sum
        u16* dp = out + (rowbase + row) * 1024 + nh * 64 + fr;
#pragma unroll
        for (int nf = 0; nf < 4; ++nf)
          dp[nf * 16] = f2bf(acc[mf][nf][r] * inv);
      }
    }
}

// ---------------- im2col for 3x3 pad-1 conv: g[B,28,28,512](bf16) -> im[6272, 4608] ----------------
__global__ __launch_bounds__(256) void k_im2col(const u16* __restrict__ g, u16* __restrict__ im){
  int idx = blockIdx.x * 256 + threadIdx.x;
  int p  = idx / 576;
  int c8 = idx - p * 576;
  int k0 = c8 << 3;
  int t9 = k0 >> 9;
  int ci = k0 & 511;
  int ky = t9 / 3, kx = t9 - ky * 3;
  int bb = p / 784;
  int s = p - bb * 784;
  int h = s / 28, w = s - h * 28;
  int hh = h + ky - 1, ww = w + kx - 1;
  uint4 val = make_uint4(0u, 0u, 0u, 0u);
  if ((unsigned)hh < 28u && (unsigned)ww < 28u)
    val = *(const uint4*)&g[(((size_t)(bb * 28 + hh)) * 28 + ww) * 512 + ci];
  *(uint4*)&im[(size_t)p * 4608 + k0] = val;
}

// ---------------- orchestration ----------------
extern "C" void kernel_launch(void* const* d_in, const int* in_sizes, int n_in,
                              void* d_out, int out_size, void* d_ws, size_t ws_size,
                              hipStream_t stream)
{
  (void)in_sizes; (void)n_in; (void)out_size; (void)ws_size;
  const float* x      = (const float*)d_in[0];
  const float* n1w    = (const float*)d_in[1];
  const float* n1b    = (const float*)d_in[2];
  const float* qkv_w  = (const float*)d_in[3];
  const float* qkv_b  = (const float*)d_in[4];
  const float* proj_w = (const float*)d_in[5];
  const float* proj_b = (const float*)d_in[6];
  const float* rel_h  = (const float*)d_in[7];
  const float* rel_w  = (const float*)d_in[8];
  const float* n2w    = (const float*)d_in[9];
  const float* n2b    = (const float*)d_in[10];
  const float* fc1_w  = (const float*)d_in[11];
  const float* fc1_b  = (const float*)d_in[12];
  const float* fc2_w  = (const float*)d_in[13];
  const float* fc2_b  = (const float*)d_in[14];
  const float* c1w    = (const float*)d_in[15];
  const float* l1w    = (const float*)d_in[16];
  const float* l1b    = (const float*)d_in[17];
  const float* c2w    = (const float*)d_in[18];
  const float* l2w    = (const float*)d_in[19];
  const float* l2b    = (const float*)d_in[20];
  const float* c3w    = (const float*)d_in[21];
  const float* l3w    = (const float*)d_in[22];
  const float* l3b    = (const float*)d_in[23];

  char* ws = (char*)d_ws;
  size_t off = 0;
  auto alloc = [&](size_t bytes) -> void* {
    void* p = ws + off; off += (bytes + 255) & ~(size_t)255; return p;
  };
  const size_t M = 6272;
  u16* qkvT  = (u16*)alloc((size_t)3072 * 1024 * 2);
  u16* projT = (u16*)alloc((size_t)1024 * 1024 * 2);
  u16* fc1T  = (u16*)alloc((size_t)4096 * 1024 * 2);
  u16* fc2T  = (u16*)alloc((size_t)1024 * 4096 * 2);
  u16* c1T   = (u16*)alloc((size_t)512 * 1024 * 2);
  u16* c2T   = (u16*)alloc((size_t)512 * 4608 * 2);
  u16* c3T   = (u16*)alloc((size_t)1024 * 512 * 2);
  u16* qkvbuf = (u16*)alloc(M * 3072 * 2);
  u16* attn   = (u16*)alloc(M * 1024 * 2);
  u16* xn     = (u16*)alloc(M * 1024 * 2);
  float* x1   = (float*)alloc(M * 1024 * 4);
  u16* x2b    = (u16*)alloc(M * 1024 * 2);
  u16* c1buf  = (u16*)alloc(M * 512 * 2);
  u16* g1buf  = (u16*)alloc(M * 512 * 2);
  u16* hmlp   = qkvbuf;
  u16* im     = qkvbuf;
  u16* xn2    = xn;
  u16* c2buf  = c1buf;
  u16* g2buf  = g1buf;
  u16* c3buf  = attn;
  // vtg (13.6 MB) aliases x1 (25.7 MB): x1 is dead until the proj GEMM, which runs after attn.
  u16* vtg    = (u16*)x1;

  dim3 blk(256);
  k_transpose<<<dim3(3072/32, 1024/32), blk, 0, stream>>>(qkv_w, qkvT, 1024, 3072);
  k_transpose<<<dim3(1024/32, 1024/32), blk, 0, stream>>>(proj_w, projT, 1024, 1024);
  k_transpose<<<dim3(4096/32, 1024/32), blk, 0, stream>>>(fc1_w, fc1T, 1024, 4096);
  k_transpose<<<dim3(1024/32, 4096/32), blk, 0, stream>>>(fc2_w, fc2T, 4096, 1024);
  k_transpose<<<dim3(512/32, 1024/32),  blk, 0, stream>>>(c1w, c1T, 1024, 512);
  k_transpose<<<dim3(512/32, 4608/32),  blk, 0, stream>>>(c2w, c2T, 4608, 512);
  k_transpose<<<dim3(1024/32, 512/32),  blk, 0, stream>>>(c3w, c3T, 512, 1024);

  k_layernorm<true,false><<<6272, blk, 0, stream>>>(x, n1w, n1b, xn, 1024, 1e-5f);
  k_gemm<true,false,false,true,false><<<dim3(24,49), blk, 0, stream>>>(
      xn, qkvT, qkv_b, nullptr, qkvbuf, nullptr, 3072, 1024);
  k_vtrans<<<dim3(128, 13), blk, 0, stream>>>(qkvbuf, vtg);
  k_attn6<<<3200, dim3(64), 0, stream>>>(qkvbuf, rel_h, rel_w, vtg, attn);
  k_gemm<true,false,true,false,true><<<dim3(8,49), blk, 0, stream>>>(
      attn, projT, proj_b, x, nullptr, x1, 1024, 1024);
  k_layernorm<true,false><<<6272, blk, 0, stream>>>(x1, n2w, n2b, xn2, 1024, 1e-5f);
  k_gemm<true,true,false,true,false><<<dim3(32,49), blk, 0, stream>>>(
      xn2, fc1T, fc1_b, nullptr, hmlp, nullptr, 4096, 1024);
  k_gemm<true,false,true,true,false><<<dim3(8,49), blk, 0, stream>>>(
      hmlp, fc2T, fc2_b, x1, x2b, nullptr, 1024, 4096);
  k_gemm<false,false,false,true,false><<<dim3(4,49), blk, 0, stream>>>(
      x2b, c1T, nullptr, nullptr, c1buf, nullptr, 512, 1024);
  k_layernorm<false,true><<<6272, blk, 0, stream>>>(c1buf, l1w, l1b, g1buf, 512, 1e-6f);
  k_im2col<<<14112, blk, 0, stream>>>(g1buf, im);
  k_gemm<false,false,false,true,false><<<dim3(4,49), blk, 0, stream>>>(
      im, c2T, nullptr, nullptr, c2buf, nullptr, 512, 4608);
  k_layernorm<false,true><<<6272, blk, 0, stream>>>(c2buf, l2w, l2b, g2buf, 512, 1e-6f);
  k_gemm<false,false,false,true,false><<<dim3(8,49), blk, 0, stream>>>(
      g2buf, c3T, nullptr, nullptr, c3buf, nullptr, 1024, 512);
  k_final<<<6272, blk, 0, stream>>>(c3buf, x2b, l3w, l3b, (float*)d_out);
}

// Round 5
// 725.590 us; speedup vs baseline: 1.0494x; 1.0494x over previous
//
#include <hip/hip_runtime.h>
#include <cstdint>
#include <cstddef>

using u16 = unsigned short;
using u32 = unsigned int;

// ---------------- helpers ----------------
__device__ __forceinline__ float bf2f(u16 u){
  union { u32 i; float f; } x; x.i = ((u32)u) << 16; return x.f;
}
__device__ __forceinline__ u16 f2bf(float f){
  union { float f; u32 i; } x; x.f = f;
  u32 r = x.i + 0x7fffu + ((x.i >> 16) & 1u);
  return (u16)(r >> 16);
}
__device__ __forceinline__ float gelu_f(float x){
  return 0.5f * x * (1.0f + erff(x * 0.70710678118654752f));
}
__device__ __forceinline__ void gld16(const void* g, void* l){
  // async global->LDS, 16B/lane; LDS dst = wave-uniform base + lane*16; global src per-lane
  __builtin_amdgcn_global_load_lds((__attribute__((address_space(1))) void*)(void*)g,
                                   (__attribute__((address_space(3))) void*)l, 16, 0, 0);
}

typedef __bf16 bf16x8 __attribute__((ext_vector_type(8)));
typedef float  f32x4  __attribute__((ext_vector_type(4)));
typedef u16    u16x4  __attribute__((ext_vector_type(4)));

// ---------------- weight transpose + cast: src fp32 [R,C] -> dst bf16 [C,R] ----------------
__global__ __launch_bounds__(256) void k_transpose(const float* __restrict__ src,
                                                   u16* __restrict__ dst, int R, int C){
  __shared__ u16 tile[32][33];
  int bx = blockIdx.x * 32;
  int by = blockIdx.y * 32;
  int tx = threadIdx.x & 31;
  int ty = threadIdx.x >> 5;
  for (int r = ty; r < 32; r += 8)
    tile[r][tx] = f2bf(src[(size_t)(by + r) * C + bx + tx]);
  __syncthreads();
  for (int r = ty; r < 32; r += 8)
    dst[(size_t)(bx + r) * R + by + tx] = tile[tx][r];
}

// ---------------- layernorm over last dim (cols = 1024 or 512), optional gelu, bf16 out ----------------
template<bool IN_F32, bool DO_GELU>
__global__ __launch_bounds__(256) void k_layernorm(const void* __restrict__ inp,
    const float* __restrict__ w, const float* __restrict__ bsh,
    u16* __restrict__ out, int cols, float eps){
  int row = blockIdx.x, t = threadIdx.x;
  size_t base = (size_t)row * cols;
  const float* inf = (const float*)inp;
  const u16*  inb = (const u16*)inp;
  float v[4];
  int ep = cols >> 8;
  float s = 0.f, ss = 0.f;
  for (int e = 0; e < ep; ++e){
    int idx = t + (e << 8);
    float x = IN_F32 ? inf[base + idx] : bf2f(inb[base + idx]);
    v[e] = x; s += x; ss += x * x;
  }
#pragma unroll
  for (int off = 1; off < 64; off <<= 1){
    s  += __shfl_xor(s, off, 64);
    ss += __shfl_xor(ss, off, 64);
  }
  __shared__ float red[8];
  int wv = t >> 6;
  if ((t & 63) == 0){ red[wv] = s; red[4 + wv] = ss; }
  __syncthreads();
  s  = red[0] + red[1] + red[2] + red[3];
  ss = red[4] + red[5] + red[6] + red[7];
  float inv = 1.f / (float)cols;
  float mean = s * inv;
  float var = ss * inv - mean * mean;
  float rs = rsqrtf(var + eps);
  for (int e = 0; e < ep; ++e){
    int idx = t + (e << 8);
    float y = (v[e] - mean) * rs * w[idx] + bsh[idx];
    if (DO_GELU) y = gelu_f(y);
    out[base + idx] = f2bf(y);
  }
}

// ---------------- final: out(fp32) = x2(bf16) + LN(c3; ln3) , cols=1024 ----------------
__global__ __launch_bounds__(256) void k_final(const u16* __restrict__ c3,
    const u16* __restrict__ x2, const float* __restrict__ w,
    const float* __restrict__ bsh, float* __restrict__ out){
  int row = blockIdx.x, t = threadIdx.x;
  size_t base = (size_t)row << 10;
  float v[4];
  float s = 0.f, ss = 0.f;
#pragma unroll
  for (int e = 0; e < 4; ++e){
    int idx = t + (e << 8);
    float x = bf2f(c3[base + idx]);
    v[e] = x; s += x; ss += x * x;
  }
#pragma unroll
  for (int off = 1; off < 64; off <<= 1){
    s  += __shfl_xor(s, off, 64);
    ss += __shfl_xor(ss, off, 64);
  }
  __shared__ float red[8];
  int wv = t >> 6;
  if ((t & 63) == 0){ red[wv] = s; red[4 + wv] = ss; }
  __syncthreads();
  s  = red[0] + red[1] + red[2] + red[3];
  ss = red[4] + red[5] + red[6] + red[7];
  float mean = s * (1.f/1024.f);
  float var = ss * (1.f/1024.f) - mean * mean;
  float rs = rsqrtf(var + 1e-6f);
#pragma unroll
  for (int e = 0; e < 4; ++e){
    int idx = t + (e << 8);
    float y = (v[e] - mean) * rs * w[idx] + bsh[idx];
    out[base + idx] = bf2f(x2[base + idx]) + y;
  }
}

// ---------------- MFMA GEMM: C[M,N] = A[M,K](bf16) * Bt[N,K]^T(bf16) (+fp32 bias/res, gelu) ----------------
// m97 structure: 128x128 tile, BK=32, 4 waves (2x2 of 64x64), global_load_lds width 16.
// XCD-aware bijective block swizzle (T1/m204).
template<bool BIAS, bool GELU, bool RES, bool OUTB, bool OUTF>
__global__ __launch_bounds__(256, 2) void k_gemm(
    const u16* __restrict__ A, const u16* __restrict__ Bt,
    const float* __restrict__ bias, const float* __restrict__ resf,
    u16* __restrict__ outb, float* __restrict__ outf, int N, int K)
{
  __shared__ __align__(16) u16 As[128 * 32];
  __shared__ __align__(16) u16 Bs[128 * 32];
  int t = threadIdx.x, lane = t & 63, wv = t >> 6;

  int nbx = gridDim.x;
  int nwg = nbx * gridDim.y;
  int li  = blockIdx.y * nbx + blockIdx.x;
  int qc = nwg >> 3, rc = nwg & 7;
  int xcd = li & 7, jj = li >> 3;
  int wg = (xcd < rc ? xcd * (qc + 1) : rc * (qc + 1) + (xcd - rc) * qc) + jj;
  int byy = wg / nbx;
  int bxx = wg - byy * nbx;
  int m0 = byy << 7, n0 = bxx << 7;

  int wm = (wv >> 1) << 6, wn = (wv & 1) << 6;

  f32x4 acc[4][4];
  const f32x4 z4 = {0.f, 0.f, 0.f, 0.f};
#pragma unroll
  for (int i = 0; i < 4; ++i)
#pragma unroll
    for (int j = 0; j < 4; ++j) acc[i][j] = z4;

  int srow = (wv << 5) + (lane >> 2);
  int skp  = (lane & 3) << 3;
  const u16* Ag = A  + (size_t)(m0 + srow) * K + skp;
  const u16* Bg = Bt + (size_t)(n0 + srow) * K + skp;
  u16* As0 = &As[(wv << 5) * 32];
  u16* As1 = As0 + 16 * 32;
  u16* Bs0 = &Bs[(wv << 5) * 32];
  u16* Bs1 = Bs0 + 16 * 32;
  const size_t rowskip = (size_t)16 * K;

  int fr = lane & 15, fq = (lane >> 4) << 3;

  for (int k0 = 0; k0 < K; k0 += 32){
    gld16(Ag + k0, As0);
    gld16(Ag + rowskip + k0, As1);
    gld16(Bg + k0, Bs0);
    gld16(Bg + rowskip + k0, Bs1);
    __syncthreads();
    bf16x8 af[4], bfr[4];
#pragma unroll
    for (int i = 0; i < 4; ++i)
      af[i] = *(const bf16x8*)&As[(wm + i * 16 + fr) * 32 + fq];
#pragma unroll
    for (int j = 0; j < 4; ++j)
      bfr[j] = *(const bf16x8*)&Bs[(wn + j * 16 + fr) * 32 + fq];
#pragma unroll
    for (int i = 0; i < 4; ++i)
#pragma unroll
      for (int j = 0; j < 4; ++j)
        acc[i][j] = __builtin_amdgcn_mfma_f32_16x16x32_bf16(af[i], bfr[j], acc[i][j], 0, 0, 0);
    __syncthreads();
  }

  int rr = (lane >> 4) << 2;
  int cc = lane & 15;
#pragma unroll
  for (int i = 0; i < 4; ++i)
#pragma unroll
    for (int j = 0; j < 4; ++j){
      int gc = n0 + wn + j * 16 + cc;
      float bb = BIAS ? bias[gc] : 0.f;
#pragma unroll
      for (int r = 0; r < 4; ++r){
        int gr = m0 + wm + i * 16 + rr + r;
        size_t idx = (size_t)gr * N + gc;
        float vv = acc[i][j][r] + bb;
        if (RES) vv += resf[idx];
        if (GELU) vv = gelu_f(vv);
        if (OUTF) outf[idx] = vv;
        if (OUTB) outb[idx] = f2bf(vv);
      }
    }
}

// ---------------- V pre-transpose: qkvbuf V slice -> vtg[bnh][64 d][832 j] (bf16, j zero-padded) ----------------
__global__ __launch_bounds__(256) void k_vtrans(const u16* __restrict__ qkv, u16* __restrict__ vtg){
  __shared__ u32 tile[64][33];
  int bnh = blockIdx.x;            // 0..127
  int st  = blockIdx.y;            // 0..12
  int b = bnh >> 4, nh = bnh & 15;
  int t = threadIdx.x;
  int tx = t & 31;                 // dword column (2 u16)
  int ty = t >> 5;                 // 0..7
  const u16* src = qkv + (size_t)b * 784 * 3072 + 2048 + nh * 64;
  int s0 = st << 6;
  for (int r = ty; r < 64; r += 8){
    int s = s0 + r;
    u32 val = 0u;
    if (s < 784) val = *(const u32*)(src + (size_t)s * 3072 + tx * 2);
    tile[r][tx] = val;
  }
  __syncthreads();
  u16* dst = vtg + (size_t)bnh * 64 * 832 + s0;
  for (int d = ty; d < 64; d += 8){
    u32 lo = tile[2 * tx][d >> 1];
    u32 hi = tile[2 * tx + 1][d >> 1];
    u16 a  = (d & 1) ? (u16)(lo >> 16) : (u16)lo;
    u16 bb = (d & 1) ? (u16)(hi >> 16) : (u16)hi;
    u32 pk = (u32)a | ((u32)bb << 16);
    *(u32*)(dst + (size_t)d * 832 + 2 * tx) = pk;
  }
}

// ---------------- MFMA flash attention v7: coalesced LDS staging + XOR swizzle ----------------
// 4-wave blocks (128 q-rows), K/V^T tiles staged per kt via global_load_lds (1KB coalesced
// transactions), LDS reads XOR-swizzled (T2, pre-swizzled global source per rule #21).
#define PST 72
#define GSTR 132
#define LOG2E 1.4426950408889634f
__global__ __launch_bounds__(256, 3) void k_attn7(const u16* __restrict__ qkv,
    const float* __restrict__ relh, const float* __restrict__ relw,
    const u16* __restrict__ vtg, u16* __restrict__ out)
{
  __shared__ __align__(16) u16 k_s[64 * 64];        // 8 KB, swizzled K tile (row j, col d)
  __shared__ __align__(16) u16 v_s[64 * 64];        // 8 KB, swizzled V^T tile (row d, col j)
  __shared__ __align__(16) u16 p_s[128 * PST];      // 18.4 KB, P; also Rh/Rw staging
  __shared__ __align__(16) u16 gh_t[28 * GSTR];     // 7.4 KB, transposed bias (x log2e)
  __shared__ __align__(16) u16 gw_t[28 * GSTR];     // 7.4 KB

  const int t = threadIdx.x, lane = t & 63, wv = t >> 6;
  int id = blockIdx.x;
  int xr = id & 7, rest = id >> 3;
  int qt = rest % 7, gg = rest / 7;
  int bnh = xr + (gg << 3);
  const int b = bnh >> 4, nh = bnh & 15;
  const int q0 = qt << 7;
  const size_t rowbase = (size_t)b * 784;
  const int wq0 = wv << 5;
  const int fr = lane & 15;
  const int fq = lane >> 4;

  // stage Rh/Rw (bf16) into p_s region
  u16* rh_s = p_s;
  u16* rw_s = p_s + 64 * PST;
  {
    int row = t >> 2, c0 = (t & 3) << 4;
    u16 bh_[16], bw_[16];
    if (row < 55){
      const float* ph = relh + row * 64 + c0;
      const float* pw = relw + row * 64 + c0;
#pragma unroll
      for (int e = 0; e < 16; ++e){ bh_[e] = f2bf(ph[e]); bw_[e] = f2bf(pw[e]); }
    } else {
#pragma unroll
      for (int e = 0; e < 16; ++e){ bh_[e] = 0; bw_[e] = 0; }
    }
    *(uint4*)&rh_s[row * PST + c0]     = *(uint4*)bh_;
    *(uint4*)&rh_s[row * PST + c0 + 8] = *(uint4*)(bh_ + 8);
    *(uint4*)&rw_s[row * PST + c0]     = *(uint4*)bw_;
    *(uint4*)&rw_s[row * PST + c0 + 8] = *(uint4*)(bw_ + 8);
  }

  // Q fragments (registers)
  bf16x8 qf[2][2];
#pragma unroll
  for (int mf = 0; mf < 2; ++mf)
#pragma unroll
    for (int ks = 0; ks < 2; ++ks){
      int row = q0 + wq0 + mf * 16 + fr;
      if (row < 784){
        qf[mf][ks] = *(const bf16x8*)(qkv + (rowbase + row) * 3072 + nh * 64 + fq * 8 + ks * 32);
      } else {
        uint4 z = {0u,0u,0u,0u}; qf[mf][ks] = *(bf16x8*)&z;
      }
    }
  __syncthreads();

  const f32x4 z4 = {0.f,0.f,0.f,0.f};
  // ---- decomposed rel-pos bias via MFMA -> transposed tables gt[kk][lr], pre-scaled by log2e ----
#pragma unroll
  for (int which = 0; which < 2; ++which){
    const u16* rs = which ? rw_s : rh_s;
    f32x4 G[2][4];
#pragma unroll
    for (int mf = 0; mf < 2; ++mf)
#pragma unroll
      for (int nf = 0; nf < 4; ++nf) G[mf][nf] = z4;
#pragma unroll
    for (int nf = 0; nf < 4; ++nf){
      bf16x8 rf0 = *(const bf16x8*)&rs[(nf * 16 + fr) * PST + fq * 8];
      bf16x8 rf1 = *(const bf16x8*)&rs[(nf * 16 + fr) * PST + fq * 8 + 32];
#pragma unroll
      for (int mf = 0; mf < 2; ++mf){
        G[mf][nf] = __builtin_amdgcn_mfma_f32_16x16x32_bf16(qf[mf][0], rf0, G[mf][nf], 0, 0, 0);
        G[mf][nf] = __builtin_amdgcn_mfma_f32_16x16x32_bf16(qf[mf][1], rf1, G[mf][nf], 0, 0, 0);
      }
    }
    u16* gt = which ? gw_t : gh_t;
#pragma unroll
    for (int mf = 0; mf < 2; ++mf)
#pragma unroll
      for (int r = 0; r < 4; ++r){
        int lr = wq0 + mf * 16 + fq * 4 + r;
        int grow = q0 + lr;
        int hq = grow / 28;
        int coord = which ? (grow - hq * 28) : hq;
#pragma unroll
        for (int nf = 0; nf < 4; ++nf){
          int j = nf * 16 + fr;
          int kk = coord + 27 - j;
          if ((unsigned)kk < 28u) gt[kk * GSTR + lr] = f2bf(G[mf][nf][r] * LOG2E);
        }
      }
  }
  __syncthreads();   // tables + Rh/Rw reads complete before p_s reuse / k_s staging

  f32x4 acc[2][5];
#pragma unroll
  for (int mf = 0; mf < 2; ++mf)
#pragma unroll
    for (int nf = 0; nf < 5; ++nf) acc[mf][nf] = z4;

  u16 onesu[8];
#pragma unroll
  for (int e = 0; e < 8; ++e) onesu[e] = 0x3f80;
  bf16x8 onesf = *(bf16x8*)onesu;

  // staging decomposition: lane -> (sub-row sr, swizzled 16B slot sc)
  const int sr = lane >> 3;                 // 0..7
  const int sc = (lane & 7) ^ sr;           // pre-swizzled source slot (involution)
  const u16* kstage = qkv + rowbase * 3072 + 1024 + nh * 64;       // + row*3072 + sc*8
  const u16* vstage = vtg + (size_t)bnh * 64 * 832;                // + d*832 + ktb + sc*8
  const int r0 = (wv << 4) + sr;            // this wave stages rows [wv*16, wv*16+16)
  u16* kd0 = &k_s[(wv << 4) * 64];
  u16* kd1 = &k_s[((wv << 4) + 8) * 64];
  u16* vd0 = &v_s[(wv << 4) * 64];
  u16* vd1 = &v_s[((wv << 4) + 8) * 64];
  const int swz = (fr & 7);                 // fragment-read swizzle key

  const float SSC = 0.125f * LOG2E;

  for (int kt = 0; kt < 13; ++kt){
    const int ktb = kt << 6;
    __syncthreads();                        // WAR: previous tile fully consumed
    {
      int jg0 = ktb + r0;       int jc0 = jg0 < 784 ? jg0 : 783;
      int jg1 = jg0 + 8;        int jc1 = jg1 < 784 ? jg1 : 783;
      gld16(kstage + (size_t)jc0 * 3072 + (sc << 3), kd0);
      gld16(kstage + (size_t)jc1 * 3072 + (sc << 3), kd1);
      gld16(vstage + (size_t)r0 * 832 + ktb + (sc << 3), vd0);
      gld16(vstage + (size_t)(r0 + 8) * 832 + ktb + (sc << 3), vd1);
    }
    __syncthreads();                        // staging visible (implicit vmcnt drain)

    // QK^T from swizzled LDS
    f32x4 S[2][4];
#pragma unroll
    for (int nf = 0; nf < 4; ++nf){
      int rb = (nf * 16 + fr) << 6;
      bf16x8 kf0 = *(const bf16x8*)&k_s[rb + ((fq ^ swz) << 3)];
      bf16x8 kf1 = *(const bf16x8*)&k_s[rb + (((fq + 4) ^ swz) << 3)];
#pragma unroll
      for (int mf = 0; mf < 2; ++mf){
        f32x4 s = z4;
        s = __builtin_amdgcn_mfma_f32_16x16x32_bf16(qf[mf][0], kf0, s, 0, 0, 0);
        s = __builtin_amdgcn_mfma_f32_16x16x32_bf16(qf[mf][1], kf1, s, 0, 0, 0);
        S[mf][nf] = s;
      }
    }

    int hj[4], wj[4]; bool val[4];
#pragma unroll
    for (int nf = 0; nf < 4; ++nf){
      int jg = ktb + nf * 16 + fr;
      int h = jg / 28;
      hj[nf] = h; wj[nf] = jg - h * 28; val[nf] = (jg < 784);
    }

    // p = exp2(SSC*S + bias2); bias via b64 reads of transposed tables
#pragma unroll
    for (int mf = 0; mf < 2; ++mf){
      int lrb = wq0 + mf * 16 + fq * 4;
#pragma unroll
      for (int nf = 0; nf < 4; ++nf){
        u16x4 h4 = *(const u16x4*)&gh_t[hj[nf] * GSTR + lrb];
        u16x4 w4 = *(const u16x4*)&gw_t[wj[nf] * GSTR + lrb];
#pragma unroll
        for (int r = 0; r < 4; ++r){
          float p = 0.f;
          if (val[nf])
            p = exp2f(fmaf(SSC, S[mf][nf][r], bf2f(h4[r]) + bf2f(w4[r])));
          p_s[(lrb + r) * PST + nf * 16 + fr] = f2bf(p);
        }
      }
    }

    // PV: P from wave-private LDS rows, V^T fragments from swizzled LDS
#pragma unroll
    for (int ks = 0; ks < 2; ++ks){
      bf16x8 pf0 = *(const bf16x8*)&p_s[(wq0 + fr) * PST + fq * 8 + ks * 32];
      bf16x8 pf1 = *(const bf16x8*)&p_s[(wq0 + 16 + fr) * PST + fq * 8 + ks * 32];
#pragma unroll
      for (int nf = 0; nf < 4; ++nf){
        bf16x8 vf = *(const bf16x8*)&v_s[((nf * 16 + fr) << 6) + (((fq + ks * 4) ^ swz) << 3)];
        acc[0][nf] = __builtin_amdgcn_mfma_f32_16x16x32_bf16(pf0, vf, acc[0][nf], 0, 0, 0);
        acc[1][nf] = __builtin_amdgcn_mfma_f32_16x16x32_bf16(pf1, vf, acc[1][nf], 0, 0, 0);
      }
      acc[0][4] = __builtin_amdgcn_mfma_f32_16x16x32_bf16(pf0, onesf, acc[0][4], 0, 0, 0);
      acc[1][4] = __builtin_amdgcn_mfma_f32_16x16x32_bf16(pf1, onesf, acc[1][4], 0, 0, 0);
    }
  }

#pragma unroll
  for (int mf = 0; mf < 2; ++mf)
#pragma unroll
    for (int r = 0; r < 4; ++r){
      int row = q0 + wq0 + mf * 16 + fq * 4 + r;
      if (row < 784){
        float inv = 1.f / acc[mf][4][r];   // ones-fragment: every column holds the row sum
        u16* dp = out + (rowbase + row) * 1024 + nh * 64 + fr;
#pragma unroll
        for (int nf = 0; nf < 4; ++nf)
          dp[nf * 16] = f2bf(acc[mf][nf][r] * inv);
      }
    }
}

// ---------------- im2col for 3x3 pad-1 conv: g[B,28,28,512](bf16) -> im[6272, 4608] ----------------
__global__ __launch_bounds__(256) void k_im2col(const u16* __restrict__ g, u16* __restrict__ im){
  int idx = blockIdx.x * 256 + threadIdx.x;
  int p  = idx / 576;
  int c8 = idx - p * 576;
  int k0 = c8 << 3;
  int t9 = k0 >> 9;
  int ci = k0 & 511;
  int ky = t9 / 3, kx = t9 - ky * 3;
  int bb = p / 784;
  int s = p - bb * 784;
  int h = s / 28, w = s - h * 28;
  int hh = h + ky - 1, ww = w + kx - 1;
  uint4 val = make_uint4(0u, 0u, 0u, 0u);
  if ((unsigned)hh < 28u && (unsigned)ww < 28u)
    val = *(const uint4*)&g[(((size_t)(bb * 28 + hh)) * 28 + ww) * 512 + ci];
  *(uint4*)&im[(size_t)p * 4608 + k0] = val;
}

// ---------------- orchestration ----------------
extern "C" void kernel_launch(void* const* d_in, const int* in_sizes, int n_in,
                              void* d_out, int out_size, void* d_ws, size_t ws_size,
                              hipStream_t stream)
{
  (void)in_sizes; (void)n_in; (void)out_size; (void)ws_size;
  const float* x      = (const float*)d_in[0];
  const float* n1w    = (const float*)d_in[1];
  const float* n1b    = (const float*)d_in[2];
  const float* qkv_w  = (const float*)d_in[3];
  const float* qkv_b  = (const float*)d_in[4];
  const float* proj_w = (const float*)d_in[5];
  const float* proj_b = (const float*)d_in[6];
  const float* rel_h  = (const float*)d_in[7];
  const float* rel_w  = (const float*)d_in[8];
  const float* n2w    = (const float*)d_in[9];
  const float* n2b    = (const float*)d_in[10];
  const float* fc1_w  = (const float*)d_in[11];
  const float* fc1_b  = (const float*)d_in[12];
  const float* fc2_w  = (const float*)d_in[13];
  const float* fc2_b  = (const float*)d_in[14];
  const float* c1w    = (const float*)d_in[15];
  const float* l1w    = (const float*)d_in[16];
  const float* l1b    = (const float*)d_in[17];
  const float* c2w    = (const float*)d_in[18];
  const float* l2w    = (const float*)d_in[19];
  const float* l2b    = (const float*)d_in[20];
  const float* c3w    = (const float*)d_in[21];
  const float* l3w    = (const float*)d_in[22];
  const float* l3b    = (const float*)d_in[23];

  char* ws = (char*)d_ws;
  size_t off = 0;
  auto alloc = [&](size_t bytes) -> void* {
    void* p = ws + off; off += (bytes + 255) & ~(size_t)255; return p;
  };
  const size_t M = 6272;
  u16* qkvT  = (u16*)alloc((size_t)3072 * 1024 * 2);
  u16* projT = (u16*)alloc((size_t)1024 * 1024 * 2);
  u16* fc1T  = (u16*)alloc((size_t)4096 * 1024 * 2);
  u16* fc2T  = (u16*)alloc((size_t)1024 * 4096 * 2);
  u16* c1T   = (u16*)alloc((size_t)512 * 1024 * 2);
  u16* c2T   = (u16*)alloc((size_t)512 * 4608 * 2);
  u16* c3T   = (u16*)alloc((size_t)1024 * 512 * 2);
  u16* qkvbuf = (u16*)alloc(M * 3072 * 2);
  u16* attn   = (u16*)alloc(M * 1024 * 2);
  u16* xn     = (u16*)alloc(M * 1024 * 2);
  float* x1   = (float*)alloc(M * 1024 * 4);
  u16* x2b    = (u16*)alloc(M * 1024 * 2);
  u16* c1buf  = (u16*)alloc(M * 512 * 2);
  u16* g1buf  = (u16*)alloc(M * 512 * 2);
  u16* hmlp   = qkvbuf;
  u16* im     = qkvbuf;
  u16* xn2    = xn;
  u16* c2buf  = c1buf;
  u16* g2buf  = g1buf;
  u16* c3buf  = attn;
  // vtg (13.6 MB) aliases x1 (25.7 MB): x1 is dead until the proj GEMM, which runs after attn.
  u16* vtg    = (u16*)x1;

  dim3 blk(256);
  k_transpose<<<dim3(3072/32, 1024/32), blk, 0, stream>>>(qkv_w, qkvT, 1024, 3072);
  k_transpose<<<dim3(1024/32, 1024/32), blk, 0, stream>>>(proj_w, projT, 1024, 1024);
  k_transpose<<<dim3(4096/32, 1024/32), blk, 0, stream>>>(fc1_w, fc1T, 1024, 4096);
  k_transpose<<<dim3(1024/32, 4096/32), blk, 0, stream>>>(fc2_w, fc2T, 4096, 1024);
  k_transpose<<<dim3(512/32, 1024/32),  blk, 0, stream>>>(c1w, c1T, 1024, 512);
  k_transpose<<<dim3(512/32, 4608/32),  blk, 0, stream>>>(c2w, c2T, 4608, 512);
  k_transpose<<<dim3(1024/32, 512/32),  blk, 0, stream>>>(c3w, c3T, 512, 1024);

  k_layernorm<true,false><<<6272, blk, 0, stream>>>(x, n1w, n1b, xn, 1024, 1e-5f);
  k_gemm<true,false,false,true,false><<<dim3(24,49), blk, 0, stream>>>(
      xn, qkvT, qkv_b, nullptr, qkvbuf, nullptr, 3072, 1024);
  k_vtrans<<<dim3(128, 13), blk, 0, stream>>>(qkvbuf, vtg);
  k_attn7<<<896, blk, 0, stream>>>(qkvbuf, rel_h, rel_w, vtg, attn);
  k_gemm<true,false,true,false,true><<<dim3(8,49), blk, 0, stream>>>(
      attn, projT, proj_b, x, nullptr, x1, 1024, 1024);
  k_layernorm<true,false><<<6272, blk, 0, stream>>>(x1, n2w, n2b, xn2, 1024, 1e-5f);
  k_gemm<true,true,false,true,false><<<dim3(32,49), blk, 0, stream>>>(
      xn2, fc1T, fc1_b, nullptr, hmlp, nullptr, 4096, 1024);
  k_gemm<true,false,true,true,false><<<dim3(8,49), blk, 0, stream>>>(
      hmlp, fc2T, fc2_b, x1, x2b, nullptr, 1024, 4096);
  k_gemm<false,false,false,true,false><<<dim3(4,49), blk, 0, stream>>>(
      x2b, c1T, nullptr, nullptr, c1buf, nullptr, 512, 1024);
  k_layernorm<false,true><<<6272, blk, 0, stream>>>(c1buf, l1w, l1b, g1buf, 512, 1e-6f);
  k_im2col<<<14112, blk, 0, stream>>>(g1buf, im);
  k_gemm<false,false,false,true,false><<<dim3(4,49), blk, 0, stream>>>(
      im, c2T, nullptr, nullptr, c2buf, nullptr, 512, 4608);
  k_layernorm<false,true><<<6272, blk, 0, stream>>>(c2buf, l2w, l2b, g2buf, 512, 1e-6f);
  k_gemm<false,false,false,true,false><<<dim3(8,49), blk, 0, stream>>>(
      g2buf, c3T, nullptr, nullptr, c3buf, nullptr, 1024, 512);
  k_final<<<6272, blk, 0, stream>>>(c3buf, x2b, l3w, l3b, (float*)d_out);
}

// Round 6
// 723.909 us; speedup vs baseline: 1.0518x; 1.0023x over previous
//
#include <hip/hip_runtime.h>
#include <cstdint>
#include <cstddef>

using u16 = unsigned short;
using u32 = unsigned int;

// ---------------- helpers ----------------
__device__ __forceinline__ float bf2f(u16 u){
  union { u32 i; float f; } x; x.i = ((u32)u) << 16; return x.f;
}
__device__ __forceinline__ u16 f2bf(float f){
  union { float f; u32 i; } x; x.f = f;
  u32 r = x.i + 0x7fffu + ((x.i >> 16) & 1u);
  return (u16)(r >> 16);
}
__device__ __forceinline__ float gelu_f(float x){
  return 0.5f * x * (1.0f + erff(x * 0.70710678118654752f));
}
__device__ __forceinline__ void gld16(const void* g, void* l){
  // async global->LDS, 16B/lane; LDS dst = wave-uniform base + lane*16; global src per-lane
  __builtin_amdgcn_global_load_lds((__attribute__((address_space(1))) void*)(void*)g,
                                   (__attribute__((address_space(3))) void*)l, 16, 0, 0);
}

typedef __bf16 bf16x8 __attribute__((ext_vector_type(8)));
typedef float  f32x4  __attribute__((ext_vector_type(4)));
typedef u16    u16x4  __attribute__((ext_vector_type(4)));

// ---------------- weight transpose + cast: src fp32 [R,C] -> dst bf16 [C,R] ----------------
__global__ __launch_bounds__(256) void k_transpose(const float* __restrict__ src,
                                                   u16* __restrict__ dst, int R, int C){
  __shared__ u16 tile[32][33];
  int bx = blockIdx.x * 32;
  int by = blockIdx.y * 32;
  int tx = threadIdx.x & 31;
  int ty = threadIdx.x >> 5;
  for (int r = ty; r < 32; r += 8)
    tile[r][tx] = f2bf(src[(size_t)(by + r) * C + bx + tx]);
  __syncthreads();
  for (int r = ty; r < 32; r += 8)
    dst[(size_t)(bx + r) * R + by + tx] = tile[tx][r];
}

// ---------------- layernorm over last dim (cols = 1024 or 512), optional gelu, bf16 out ----------------
template<bool IN_F32, bool DO_GELU>
__global__ __launch_bounds__(256) void k_layernorm(const void* __restrict__ inp,
    const float* __restrict__ w, const float* __restrict__ bsh,
    u16* __restrict__ out, int cols, float eps){
  int row = blockIdx.x, t = threadIdx.x;
  size_t base = (size_t)row * cols;
  const float* inf = (const float*)inp;
  const u16*  inb = (const u16*)inp;
  float v[4];
  int ep = cols >> 8;
  float s = 0.f, ss = 0.f;
  for (int e = 0; e < ep; ++e){
    int idx = t + (e << 8);
    float x = IN_F32 ? inf[base + idx] : bf2f(inb[base + idx]);
    v[e] = x; s += x; ss += x * x;
  }
#pragma unroll
  for (int off = 1; off < 64; off <<= 1){
    s  += __shfl_xor(s, off, 64);
    ss += __shfl_xor(ss, off, 64);
  }
  __shared__ float red[8];
  int wv = t >> 6;
  if ((t & 63) == 0){ red[wv] = s; red[4 + wv] = ss; }
  __syncthreads();
  s  = red[0] + red[1] + red[2] + red[3];
  ss = red[4] + red[5] + red[6] + red[7];
  float inv = 1.f / (float)cols;
  float mean = s * inv;
  float var = ss * inv - mean * mean;
  float rs = rsqrtf(var + eps);
  for (int e = 0; e < ep; ++e){
    int idx = t + (e << 8);
    float y = (v[e] - mean) * rs * w[idx] + bsh[idx];
    if (DO_GELU) y = gelu_f(y);
    out[base + idx] = f2bf(y);
  }
}

// ---------------- final: out(fp32) = x2(bf16) + LN(c3; ln3) , cols=1024 ----------------
__global__ __launch_bounds__(256) void k_final(const u16* __restrict__ c3,
    const u16* __restrict__ x2, const float* __restrict__ w,
    const float* __restrict__ bsh, float* __restrict__ out){
  int row = blockIdx.x, t = threadIdx.x;
  size_t base = (size_t)row << 10;
  float v[4];
  float s = 0.f, ss = 0.f;
#pragma unroll
  for (int e = 0; e < 4; ++e){
    int idx = t + (e << 8);
    float x = bf2f(c3[base + idx]);
    v[e] = x; s += x; ss += x * x;
  }
#pragma unroll
  for (int off = 1; off < 64; off <<= 1){
    s  += __shfl_xor(s, off, 64);
    ss += __shfl_xor(ss, off, 64);
  }
  __shared__ float red[8];
  int wv = t >> 6;
  if ((t & 63) == 0){ red[wv] = s; red[4 + wv] = ss; }
  __syncthreads();
  s  = red[0] + red[1] + red[2] + red[3];
  ss = red[4] + red[5] + red[6] + red[7];
  float mean = s * (1.f/1024.f);
  float var = ss * (1.f/1024.f) - mean * mean;
  float rs = rsqrtf(var + 1e-6f);
#pragma unroll
  for (int e = 0; e < 4; ++e){
    int idx = t + (e << 8);
    float y = (v[e] - mean) * rs * w[idx] + bsh[idx];
    out[base + idx] = bf2f(x2[base + idx]) + y;
  }
}

// ---------------- MFMA GEMM: C[M,N] = A[M,K](bf16) * Bt[N,K]^T(bf16) (+fp32 bias/res, gelu) ----------------
// 128x128 tile, BK=32, 4 waves, double-buffered LDS (T3-minimum 2-phase):
// stage tile k+1 BEFORE computing tile k; one counted vmcnt(0)+raw barrier per phase.
// XCD-aware bijective block swizzle (T1/m204).
template<bool BIAS, bool GELU, bool RES, bool OUTB, bool OUTF>
__global__ __launch_bounds__(256, 2) void k_gemm(
    const u16* __restrict__ A, const u16* __restrict__ Bt,
    const float* __restrict__ bias, const float* __restrict__ resf,
    u16* __restrict__ outb, float* __restrict__ outf, int N, int K)
{
  __shared__ __align__(16) u16 As[2][128 * 32];
  __shared__ __align__(16) u16 Bs[2][128 * 32];
  int t = threadIdx.x, lane = t & 63, wv = t >> 6;

  int nbx = gridDim.x;
  int nwg = nbx * gridDim.y;
  int li  = blockIdx.y * nbx + blockIdx.x;
  int qc = nwg >> 3, rc = nwg & 7;
  int xcd = li & 7, jj = li >> 3;
  int wg = (xcd < rc ? xcd * (qc + 1) : rc * (qc + 1) + (xcd - rc) * qc) + jj;
  int byy = wg / nbx;
  int bxx = wg - byy * nbx;
  int m0 = byy << 7, n0 = bxx << 7;

  int wm = (wv >> 1) << 6, wn = (wv & 1) << 6;

  f32x4 acc[4][4];
  const f32x4 z4 = {0.f, 0.f, 0.f, 0.f};
#pragma unroll
  for (int i = 0; i < 4; ++i)
#pragma unroll
    for (int j = 0; j < 4; ++j) acc[i][j] = z4;

  int srow = (wv << 5) + (lane >> 2);
  int skp  = (lane & 3) << 3;
  const u16* Ag = A  + (size_t)(m0 + srow) * K + skp;
  const u16* Bg = Bt + (size_t)(n0 + srow) * K + skp;
  const size_t rowskip = (size_t)16 * K;

  int fr = lane & 15, fq = (lane >> 4) << 3;

#define G_STAGE(buf, k0) { \
    u16* a0 = &As[buf][(wv << 5) * 32]; \
    u16* b0 = &Bs[buf][(wv << 5) * 32]; \
    gld16(Ag + (k0), a0); \
    gld16(Ag + rowskip + (k0), a0 + 16 * 32); \
    gld16(Bg + (k0), b0); \
    gld16(Bg + rowskip + (k0), b0 + 16 * 32); }

#define G_COMPUTE(buf) { \
    bf16x8 af[4], bfr[4]; \
    _Pragma("unroll") \
    for (int i = 0; i < 4; ++i) \
      af[i] = *(const bf16x8*)&As[buf][(wm + i * 16 + fr) * 32 + fq]; \
    _Pragma("unroll") \
    for (int j = 0; j < 4; ++j) \
      bfr[j] = *(const bf16x8*)&Bs[buf][(wn + j * 16 + fr) * 32 + fq]; \
    _Pragma("unroll") \
    for (int i = 0; i < 4; ++i) \
      _Pragma("unroll") \
      for (int j = 0; j < 4; ++j) \
        acc[i][j] = __builtin_amdgcn_mfma_f32_16x16x32_bf16(af[i], bfr[j], acc[i][j], 0, 0, 0); }

#define G_PHASE_END() { \
    asm volatile("s_waitcnt vmcnt(0) lgkmcnt(0)" ::: "memory"); \
    __builtin_amdgcn_s_barrier(); }

  // prologue: stage tile 0
  G_STAGE(0, 0);
  G_PHASE_END();

  int nk = K >> 5;                 // all K are multiples of 64 -> nk even
  for (int kk = 0; kk < nk; kk += 2){
    // phase A: stage kk+1 into buf1 (flies under compute), compute buf0
    if (kk + 1 < nk) G_STAGE(1, (kk + 1) << 5);
    G_COMPUTE(0);
    G_PHASE_END();
    // phase B: stage kk+2 into buf0, compute buf1
    if (kk + 2 < nk) G_STAGE(0, (kk + 2) << 5);
    if (kk + 1 < nk){
      G_COMPUTE(1);
      G_PHASE_END();
    }
  }

#undef G_STAGE
#undef G_COMPUTE
#undef G_PHASE_END

  int rr = (lane >> 4) << 2;
  int cc = lane & 15;
#pragma unroll
  for (int i = 0; i < 4; ++i)
#pragma unroll
    for (int j = 0; j < 4; ++j){
      int gc = n0 + wn + j * 16 + cc;
      float bb = BIAS ? bias[gc] : 0.f;
#pragma unroll
      for (int r = 0; r < 4; ++r){
        int gr = m0 + wm + i * 16 + rr + r;
        size_t idx = (size_t)gr * N + gc;
        float vv = acc[i][j][r] + bb;
        if (RES) vv += resf[idx];
        if (GELU) vv = gelu_f(vv);
        if (OUTF) outf[idx] = vv;
        if (OUTB) outb[idx] = f2bf(vv);
      }
    }
}

// ---------------- V pre-transpose: qkvbuf V slice -> vtg[bnh][64 d][832 j] (bf16, j zero-padded) ----------------
__global__ __launch_bounds__(256) void k_vtrans(const u16* __restrict__ qkv, u16* __restrict__ vtg){
  __shared__ u32 tile[64][33];
  int bnh = blockIdx.x;            // 0..127
  int st  = blockIdx.y;            // 0..12
  int b = bnh >> 4, nh = bnh & 15;
  int t = threadIdx.x;
  int tx = t & 31;                 // dword column (2 u16)
  int ty = t >> 5;                 // 0..7
  const u16* src = qkv + (size_t)b * 784 * 3072 + 2048 + nh * 64;
  int s0 = st << 6;
  for (int r = ty; r < 64; r += 8){
    int s = s0 + r;
    u32 val = 0u;
    if (s < 784) val = *(const u32*)(src + (size_t)s * 3072 + tx * 2);
    tile[r][tx] = val;
  }
  __syncthreads();
  u16* dst = vtg + (size_t)bnh * 64 * 832 + s0;
  for (int d = ty; d < 64; d += 8){
    u32 lo = tile[2 * tx][d >> 1];
    u32 hi = tile[2 * tx + 1][d >> 1];
    u16 a  = (d & 1) ? (u16)(lo >> 16) : (u16)lo;
    u16 bb = (d & 1) ? (u16)(hi >> 16) : (u16)hi;
    u32 pk = (u32)a | ((u32)bb << 16);
    *(u32*)(dst + (size_t)d * 832 + 2 * tx) = pk;
  }
}

// ---------------- MFMA flash attention v7: coalesced LDS staging + XOR swizzle ----------------
#define PST 72
#define GSTR 132
#define LOG2E 1.4426950408889634f
__global__ __launch_bounds__(256, 3) void k_attn7(const u16* __restrict__ qkv,
    const float* __restrict__ relh, const float* __restrict__ relw,
    const u16* __restrict__ vtg, u16* __restrict__ out)
{
  __shared__ __align__(16) u16 k_s[64 * 64];        // 8 KB, swizzled K tile (row j, col d)
  __shared__ __align__(16) u16 v_s[64 * 64];        // 8 KB, swizzled V^T tile (row d, col j)
  __shared__ __align__(16) u16 p_s[128 * PST];      // 18.4 KB, P; also Rh/Rw staging
  __shared__ __align__(16) u16 gh_t[28 * GSTR];     // 7.4 KB, transposed bias (x log2e)
  __shared__ __align__(16) u16 gw_t[28 * GSTR];     // 7.4 KB

  const int t = threadIdx.x, lane = t & 63, wv = t >> 6;
  int id = blockIdx.x;
  int xr = id & 7, rest = id >> 3;
  int qt = rest % 7, gg = rest / 7;
  int bnh = xr + (gg << 3);
  const int b = bnh >> 4, nh = bnh & 15;
  const int q0 = qt << 7;
  const size_t rowbase = (size_t)b * 784;
  const int wq0 = wv << 5;
  const int fr = lane & 15;
  const int fq = lane >> 4;

  // stage Rh/Rw (bf16) into p_s region
  u16* rh_s = p_s;
  u16* rw_s = p_s + 64 * PST;
  {
    int row = t >> 2, c0 = (t & 3) << 4;
    u16 bh_[16], bw_[16];
    if (row < 55){
      const float* ph = relh + row * 64 + c0;
      const float* pw = relw + row * 64 + c0;
#pragma unroll
      for (int e = 0; e < 16; ++e){ bh_[e] = f2bf(ph[e]); bw_[e] = f2bf(pw[e]); }
    } else {
#pragma unroll
      for (int e = 0; e < 16; ++e){ bh_[e] = 0; bw_[e] = 0; }
    }
    *(uint4*)&rh_s[row * PST + c0]     = *(uint4*)bh_;
    *(uint4*)&rh_s[row * PST + c0 + 8] = *(uint4*)(bh_ + 8);
    *(uint4*)&rw_s[row * PST + c0]     = *(uint4*)bw_;
    *(uint4*)&rw_s[row * PST + c0 + 8] = *(uint4*)(bw_ + 8);
  }

  // Q fragments (registers)
  bf16x8 qf[2][2];
#pragma unroll
  for (int mf = 0; mf < 2; ++mf)
#pragma unroll
    for (int ks = 0; ks < 2; ++ks){
      int row = q0 + wq0 + mf * 16 + fr;
      if (row < 784){
        qf[mf][ks] = *(const bf16x8*)(qkv + (rowbase + row) * 3072 + nh * 64 + fq * 8 + ks * 32);
      } else {
        uint4 z = {0u,0u,0u,0u}; qf[mf][ks] = *(bf16x8*)&z;
      }
    }
  __syncthreads();

  const f32x4 z4 = {0.f,0.f,0.f,0.f};
  // ---- decomposed rel-pos bias via MFMA -> transposed tables gt[kk][lr], pre-scaled by log2e ----
#pragma unroll
  for (int which = 0; which < 2; ++which){
    const u16* rs = which ? rw_s : rh_s;
    f32x4 G[2][4];
#pragma unroll
    for (int mf = 0; mf < 2; ++mf)
#pragma unroll
      for (int nf = 0; nf < 4; ++nf) G[mf][nf] = z4;
#pragma unroll
    for (int nf = 0; nf < 4; ++nf){
      bf16x8 rf0 = *(const bf16x8*)&rs[(nf * 16 + fr) * PST + fq * 8];
      bf16x8 rf1 = *(const bf16x8*)&rs[(nf * 16 + fr) * PST + fq * 8 + 32];
#pragma unroll
      for (int mf = 0; mf < 2; ++mf){
        G[mf][nf] = __builtin_amdgcn_mfma_f32_16x16x32_bf16(qf[mf][0], rf0, G[mf][nf], 0, 0, 0);
        G[mf][nf] = __builtin_amdgcn_mfma_f32_16x16x32_bf16(qf[mf][1], rf1, G[mf][nf], 0, 0, 0);
      }
    }
    u16* gt = which ? gw_t : gh_t;
#pragma unroll
    for (int mf = 0; mf < 2; ++mf)
#pragma unroll
      for (int r = 0; r < 4; ++r){
        int lr = wq0 + mf * 16 + fq * 4 + r;
        int grow = q0 + lr;
        int hq = grow / 28;
        int coord = which ? (grow - hq * 28) : hq;
#pragma unroll
        for (int nf = 0; nf < 4; ++nf){
          int j = nf * 16 + fr;
          int kk = coord + 27 - j;
          if ((unsigned)kk < 28u) gt[kk * GSTR + lr] = f2bf(G[mf][nf][r] * LOG2E);
        }
      }
  }
  __syncthreads();   // tables + Rh/Rw reads complete before p_s reuse / k_s staging

  f32x4 acc[2][5];
#pragma unroll
  for (int mf = 0; mf < 2; ++mf)
#pragma unroll
    for (int nf = 0; nf < 5; ++nf) acc[mf][nf] = z4;

  u16 onesu[8];
#pragma unroll
  for (int e = 0; e < 8; ++e) onesu[e] = 0x3f80;
  bf16x8 onesf = *(bf16x8*)onesu;

  // staging decomposition: lane -> (sub-row sr, swizzled 16B slot sc)
  const int sr = lane >> 3;                 // 0..7
  const int sc = (lane & 7) ^ sr;           // pre-swizzled source slot (involution)
  const u16* kstage = qkv + rowbase * 3072 + 1024 + nh * 64;       // + row*3072 + sc*8
  const u16* vstage = vtg + (size_t)bnh * 64 * 832;                // + d*832 + ktb + sc*8
  const int r0 = (wv << 4) + sr;            // this wave stages rows [wv*16, wv*16+16)
  u16* kd0 = &k_s[(wv << 4) * 64];
  u16* kd1 = &k_s[((wv << 4) + 8) * 64];
  u16* vd0 = &v_s[(wv << 4) * 64];
  u16* vd1 = &v_s[((wv << 4) + 8) * 64];
  const int swz = (fr & 7);                 // fragment-read swizzle key

  const float SSC = 0.125f * LOG2E;

  for (int kt = 0; kt < 13; ++kt){
    const int ktb = kt << 6;
    __syncthreads();                        // WAR: previous tile fully consumed
    {
      int jg0 = ktb + r0;       int jc0 = jg0 < 784 ? jg0 : 783;
      int jg1 = jg0 + 8;        int jc1 = jg1 < 784 ? jg1 : 783;
      gld16(kstage + (size_t)jc0 * 3072 + (sc << 3), kd0);
      gld16(kstage + (size_t)jc1 * 3072 + (sc << 3), kd1);
      gld16(vstage + (size_t)r0 * 832 + ktb + (sc << 3), vd0);
      gld16(vstage + (size_t)(r0 + 8) * 832 + ktb + (sc << 3), vd1);
    }
    __syncthreads();                        // staging visible (implicit vmcnt drain)

    // QK^T from swizzled LDS
    f32x4 S[2][4];
#pragma unroll
    for (int nf = 0; nf < 4; ++nf){
      int rb = (nf * 16 + fr) << 6;
      bf16x8 kf0 = *(const bf16x8*)&k_s[rb + ((fq ^ swz) << 3)];
      bf16x8 kf1 = *(const bf16x8*)&k_s[rb + (((fq + 4) ^ swz) << 3)];
#pragma unroll
      for (int mf = 0; mf < 2; ++mf){
        f32x4 s = z4;
        s = __builtin_amdgcn_mfma_f32_16x16x32_bf16(qf[mf][0], kf0, s, 0, 0, 0);
        s = __builtin_amdgcn_mfma_f32_16x16x32_bf16(qf[mf][1], kf1, s, 0, 0, 0);
        S[mf][nf] = s;
      }
    }

    int hj[4], wj[4]; bool val[4];
#pragma unroll
    for (int nf = 0; nf < 4; ++nf){
      int jg = ktb + nf * 16 + fr;
      int h = jg / 28;
      hj[nf] = h; wj[nf] = jg - h * 28; val[nf] = (jg < 784);
    }

    // p = exp2(SSC*S + bias2); bias via b64 reads of transposed tables
#pragma unroll
    for (int mf = 0; mf < 2; ++mf){
      int lrb = wq0 + mf * 16 + fq * 4;
#pragma unroll
      for (int nf = 0; nf < 4; ++nf){
        u16x4 h4 = *(const u16x4*)&gh_t[hj[nf] * GSTR + lrb];
        u16x4 w4 = *(const u16x4*)&gw_t[wj[nf] * GSTR + lrb];
#pragma unroll
        for (int r = 0; r < 4; ++r){
          float p = 0.f;
          if (val[nf])
            p = exp2f(fmaf(SSC, S[mf][nf][r], bf2f(h4[r]) + bf2f(w4[r])));
          p_s[(lrb + r) * PST + nf * 16 + fr] = f2bf(p);
        }
      }
    }

    // PV: P from wave-private LDS rows, V^T fragments from swizzled LDS
#pragma unroll
    for (int ks = 0; ks < 2; ++ks){
      bf16x8 pf0 = *(const bf16x8*)&p_s[(wq0 + fr) * PST + fq * 8 + ks * 32];
      bf16x8 pf1 = *(const bf16x8*)&p_s[(wq0 + 16 + fr) * PST + fq * 8 + ks * 32];
#pragma unroll
      for (int nf = 0; nf < 4; ++nf){
        bf16x8 vf = *(const bf16x8*)&v_s[((nf * 16 + fr) << 6) + (((fq + ks * 4) ^ swz) << 3)];
        acc[0][nf] = __builtin_amdgcn_mfma_f32_16x16x32_bf16(pf0, vf, acc[0][nf], 0, 0, 0);
        acc[1][nf] = __builtin_amdgcn_mfma_f32_16x16x32_bf16(pf1, vf, acc[1][nf], 0, 0, 0);
      }
      acc[0][4] = __builtin_amdgcn_mfma_f32_16x16x32_bf16(pf0, onesf, acc[0][4], 0, 0, 0);
      acc[1][4] = __builtin_amdgcn_mfma_f32_16x16x32_bf16(pf1, onesf, acc[1][4], 0, 0, 0);
    }
  }

#pragma unroll
  for (int mf = 0; mf < 2; ++mf)
#pragma unroll
    for (int r = 0; r < 4; ++r){
      int row = q0 + wq0 + mf * 16 + fq * 4 + r;
      if (row < 784){
        float inv = 1.f / acc[mf][4][r];   // ones-fragment: every column holds the row sum
        u16* dp = out + (rowbase + row) * 1024 + nh * 64 + fr;
#pragma unroll
        for (int nf = 0; nf < 4; ++nf)
          dp[nf * 16] = f2bf(acc[mf][nf][r] * inv);
      }
    }
}

// ---------------- im2col for 3x3 pad-1 conv: g[B,28,28,512](bf16) -> im[6272, 4608] ----------------
__global__ __launch_bounds__(256) void k_im2col(const u16* __restrict__ g, u16* __restrict__ im){
  int idx = blockIdx.x * 256 + threadIdx.x;
  int p  = idx / 576;
  int c8 = idx - p * 576;
  int k0 = c8 << 3;
  int t9 = k0 >> 9;
  int ci = k0 & 511;
  int ky = t9 / 3, kx = t9 - ky * 3;
  int bb = p / 784;
  int s = p - bb * 784;
  int h = s / 28, w = s - h * 28;
  int hh = h + ky - 1, ww = w + kx - 1;
  uint4 val = make_uint4(0u, 0u, 0u, 0u);
  if ((unsigned)hh < 28u && (unsigned)ww < 28u)
    val = *(const uint4*)&g[(((size_t)(bb * 28 + hh)) * 28 + ww) * 512 + ci];
  *(uint4*)&im[(size_t)p * 4608 + k0] = val;
}

// ---------------- orchestration ----------------
extern "C" void kernel_launch(void* const* d_in, const int* in_sizes, int n_in,
                              void* d_out, int out_size, void* d_ws, size_t ws_size,
                              hipStream_t stream)
{
  (void)in_sizes; (void)n_in; (void)out_size; (void)ws_size;
  const float* x      = (const float*)d_in[0];
  const float* n1w    = (const float*)d_in[1];
  const float* n1b    = (const float*)d_in[2];
  const float* qkv_w  = (const float*)d_in[3];
  const float* qkv_b  = (const float*)d_in[4];
  const float* proj_w = (const float*)d_in[5];
  const float* proj_b = (const float*)d_in[6];
  const float* rel_h  = (const float*)d_in[7];
  const float* rel_w  = (const float*)d_in[8];
  const float* n2w    = (const float*)d_in[9];
  const float* n2b    = (const float*)d_in[10];
  const float* fc1_w  = (const float*)d_in[11];
  const float* fc1_b  = (const float*)d_in[12];
  const float* fc2_w  = (const float*)d_in[13];
  const float* fc2_b  = (const float*)d_in[14];
  const float* c1w    = (const float*)d_in[15];
  const float* l1w    = (const float*)d_in[16];
  const float* l1b    = (const float*)d_in[17];
  const float* c2w    = (const float*)d_in[18];
  const float* l2w    = (const float*)d_in[19];
  const float* l2b    = (const float*)d_in[20];
  const float* c3w    = (const float*)d_in[21];
  const float* l3w    = (const float*)d_in[22];
  const float* l3b    = (const float*)d_in[23];

  char* ws = (char*)d_ws;
  size_t off = 0;
  auto alloc = [&](size_t bytes) -> void* {
    void* p = ws + off; off += (bytes + 255) & ~(size_t)255; return p;
  };
  const size_t M = 6272;
  u16* qkvT  = (u16*)alloc((size_t)3072 * 1024 * 2);
  u16* projT = (u16*)alloc((size_t)1024 * 1024 * 2);
  u16* fc1T  = (u16*)alloc((size_t)4096 * 1024 * 2);
  u16* fc2T  = (u16*)alloc((size_t)1024 * 4096 * 2);
  u16* c1T   = (u16*)alloc((size_t)512 * 1024 * 2);
  u16* c2T   = (u16*)alloc((size_t)512 * 4608 * 2);
  u16* c3T   = (u16*)alloc((size_t)1024 * 512 * 2);
  u16* qkvbuf = (u16*)alloc(M * 3072 * 2);
  u16* attn   = (u16*)alloc(M * 1024 * 2);
  u16* xn     = (u16*)alloc(M * 1024 * 2);
  float* x1   = (float*)alloc(M * 1024 * 4);
  u16* x2b    = (u16*)alloc(M * 1024 * 2);
  u16* c1buf  = (u16*)alloc(M * 512 * 2);
  u16* g1buf  = (u16*)alloc(M * 512 * 2);
  u16* hmlp   = qkvbuf;
  u16* im     = qkvbuf;
  u16* xn2    = xn;
  u16* c2buf  = c1buf;
  u16* g2buf  = g1buf;
  u16* c3buf  = attn;
  // vtg (13.6 MB) aliases x1 (25.7 MB): x1 is dead until the proj GEMM, which runs after attn.
  u16* vtg    = (u16*)x1;

  dim3 blk(256);
  k_transpose<<<dim3(3072/32, 1024/32), blk, 0, stream>>>(qkv_w, qkvT, 1024, 3072);
  k_transpose<<<dim3(1024/32, 1024/32), blk, 0, stream>>>(proj_w, projT, 1024, 1024);
  k_transpose<<<dim3(4096/32, 1024/32), blk, 0, stream>>>(fc1_w, fc1T, 1024, 4096);
  k_transpose<<<dim3(1024/32, 4096/32), blk, 0, stream>>>(fc2_w, fc2T, 4096, 1024);
  k_transpose<<<dim3(512/32, 1024/32),  blk, 0, stream>>>(c1w, c1T, 1024, 512);
  k_transpose<<<dim3(512/32, 4608/32),  blk, 0, stream>>>(c2w, c2T, 4608, 512);
  k_transpose<<<dim3(1024/32, 512/32),  blk, 0, stream>>>(c3w, c3T, 512, 1024);

  k_layernorm<true,false><<<6272, blk, 0, stream>>>(x, n1w, n1b, xn, 1024, 1e-5f);
  k_gemm<true,false,false,true,false><<<dim3(24,49), blk, 0, stream>>>(
      xn, qkvT, qkv_b, nullptr, qkvbuf, nullptr, 3072, 1024);
  k_vtrans<<<dim3(128, 13), blk, 0, stream>>>(qkvbuf, vtg);
  k_attn7<<<896, blk, 0, stream>>>(qkvbuf, rel_h, rel_w, vtg, attn);
  k_gemm<true,false,true,false,true><<<dim3(8,49), blk, 0, stream>>>(
      attn, projT, proj_b, x, nullptr, x1, 1024, 1024);
  k_layernorm<true,false><<<6272, blk, 0, stream>>>(x1, n2w, n2b, xn2, 1024, 1e-5f);
  k_gemm<true,true,false,true,false><<<dim3(32,49), blk, 0, stream>>>(
      xn2, fc1T, fc1_b, nullptr, hmlp, nullptr, 4096, 1024);
  k_gemm<true,false,true,true,false><<<dim3(8,49), blk, 0, stream>>>(
      hmlp, fc2T, fc2_b, x1, x2b, nullptr, 1024, 4096);
  k_gemm<false,false,false,true,false><<<dim3(4,49), blk, 0, stream>>>(
      x2b, c1T, nullptr, nullptr, c1buf, nullptr, 512, 1024);
  k_layernorm<false,true><<<6272, blk, 0, stream>>>(c1buf, l1w, l1b, g1buf, 512, 1e-6f);
  k_im2col<<<14112, blk, 0, stream>>>(g1buf, im);
  k_gemm<false,false,false,true,false><<<dim3(4,49), blk, 0, stream>>>(
      im, c2T, nullptr, nullptr, c2buf, nullptr, 512, 4608);
  k_layernorm<false,true><<<6272, blk, 0, stream>>>(c2buf, l2w, l2b, g2buf, 512, 1e-6f);
  k_gemm<false,false,false,true,false><<<dim3(8,49), blk, 0, stream>>>(
      g2buf, c3T, nullptr, nullptr, c3buf, nullptr, 1024, 512);
  k_final<<<6272, blk, 0, stream>>>(c3buf, x2b, l3w, l3b, (float*)d_out);
}